// Round 18
// baseline (87.265 us; speedup 1.0000x reference)
//
#include <hip/hip_runtime.h>
#include <hip/hip_bf16.h>

#define NN 4096
#define SJ 8
#define JCH (NN / SJ)        // 512
#define JSTEP 64
#define NSTEPS (JCH / JSTEP) // 8
#define LOG2E 1.44269504f

typedef __attribute__((ext_vector_type(4))) float f32x4;
typedef __attribute__((ext_vector_type(4))) int i32x4;
typedef __attribute__((ext_vector_type(4))) unsigned int u32x4;
typedef __attribute__((ext_vector_type(8))) short short8;

// packed bf16 pair: (lo=bf16(a), hi=bf16(b)) in one dword (v_cvt_pk_bf16_f32)
__device__ __forceinline__ unsigned pk2(float a, float b) {
    float2 t; t.x = a; t.y = b;
    __hip_bfloat162 h = __float22bfloat162_rn(t);
    unsigned r;
    __builtin_memcpy(&r, &h, 4);
    return r;
}

__device__ __forceinline__ short8 load8_bf(const float* __restrict__ p) {
    f32x4 a = *(const f32x4*)p;
    f32x4 b = *(const f32x4*)(p + 4);
    u32x4 v = {pk2(a[0], a[1]), pk2(a[2], a[3]), pk2(b[0], b[1]), pk2(b[2], b[3])};
    return __builtin_bit_cast(short8, v);
}

// Kernel 0: adj (64 MB of {0,1} int32) -> 2 MB bitmask via wave ballot.
// Layout: maskv[row*64 + c*4 + e] (u64) bit l  <->  adj[row][c*256 + l*4 + e].
// Wave reads 16B/lane (1KB contiguous per instr), 4 ballots, lane0 stores 32B.
__global__ __launch_bounds__(256) void k0_mask(const int* __restrict__ adj,
                                               unsigned long long* __restrict__ maskv) {
    const int wave = threadIdx.x >> 6;
    const int lane = threadIdx.x & 63;
    const int row = blockIdx.x * 4 + wave;
    const int* src = adj + (size_t)row * NN + lane * 4;
#pragma unroll 4
    for (int c = 0; c < 16; ++c) {
        const i32x4 v = *(const i32x4*)(src + c * 256);
        const unsigned long long w0 = __ballot(v[0] != 0);
        const unsigned long long w1 = __ballot(v[1] != 0);
        const unsigned long long w2 = __ballot(v[2] != 0);
        const unsigned long long w3 = __ballot(v[3] != 0);
        if (lane == 0) {
            unsigned long long* d = maskv + (size_t)row * 64 + c * 4;
            d[0] = w0; d[1] = w1; d[2] = w2; d[3] = w3;
        }
    }
}

// Kernel 1: h = x @ W^T (bf16 MFMA). Epilogue:
//   Rt[h][i]  = exp(-0.8*es_i)   (f32; exp(es) factor cancels in softmax)
//   BDt[h][j] = pack_bf16(exp(ed_j), exp(0.2*ed_j))
//   hT[h*32+d][j] = bf16 h, transposed via per-wave LDS tile (coalesced stores)
__global__ __launch_bounds__(256) void k1_proj(
        const float* __restrict__ x, const float* __restrict__ W,
        const float* __restrict__ asrc, const float* __restrict__ adst,
        unsigned short* __restrict__ hT, float* __restrict__ Rt,
        unsigned* __restrict__ BDt) {
    __shared__ unsigned short ttile[4][32][16];   // 4 KB
    const int ibase = blockIdx.x * 16;
    const int w = threadIdx.x >> 6;
    const int lane = threadIdx.x & 63;
    const int grp = lane >> 4, li = lane & 15;

    const float* xrow = x + (ibase + li) * 128;
    const float* w0 = W + (w * 32 + li) * 128;
    const float* w1 = W + (w * 32 + 16 + li) * 128;

    f32x4 c0 = {0.f, 0.f, 0.f, 0.f}, c1 = {0.f, 0.f, 0.f, 0.f};
#pragma unroll
    for (int ko = 0; ko < 128; ko += 32) {
        const int kk = ko + grp * 8;
        short8 a = load8_bf(xrow + kk);
        short8 b0 = load8_bf(w0 + kk);
        short8 b1 = load8_bf(w1 + kk);
        c0 = __builtin_amdgcn_mfma_f32_16x16x32_bf16(a, b0, c0, 0, 0, 0);
        c1 = __builtin_amdgcn_mfma_f32_16x16x32_bf16(a, b1, c1, 0, 0, 0);
    }
    const float as0 = asrc[w * 32 + li], as1 = asrc[w * 32 + 16 + li];
    const float ad0 = adst[w * 32 + li], ad1 = adst[w * 32 + 16 + li];
    float pes[4], ped[4];
#pragma unroll
    for (int r = 0; r < 4; ++r) {
        pes[r] = c0[r] * as0 + c1[r] * as1;
        ped[r] = c0[r] * ad0 + c1[r] * ad1;
    }
#pragma unroll
    for (int m = 1; m < 16; m <<= 1) {
#pragma unroll
        for (int r = 0; r < 4; ++r) {
            pes[r] += __shfl_xor(pes[r], m);
            ped[r] += __shfl_xor(ped[r], m);
        }
    }
    if (li == 0) {
#pragma unroll
        for (int r = 0; r < 4; ++r) {
            const int row = ibase + grp * 4 + r;
            Rt[w * NN + row] = __builtin_amdgcn_exp2f(-0.8f * LOG2E * pes[r]);
            const float Bv = __builtin_amdgcn_exp2f(LOG2E * ped[r]);
            const float Dv = __builtin_amdgcn_exp2f(0.2f * LOG2E * ped[r]);
            BDt[w * NN + row] = pk2(Bv, Dv);
        }
    }
    unsigned short* tw = &ttile[w][0][0];
    {
        uint2 v0; v0.x = pk2(c0[0], c0[1]); v0.y = pk2(c0[2], c0[3]);
        uint2 v1; v1.x = pk2(c1[0], c1[1]); v1.y = pk2(c1[2], c1[3]);
        *(uint2*)&tw[li * 16 + grp * 4] = v0;
        *(uint2*)&tw[(li + 16) * 16 + grp * 4] = v1;
    }
    __syncthreads();
    const int d = lane >> 1, half = lane & 1;
    u32x4 v = *(const u32x4*)&ttile[w][d][half * 8];
    *(u32x4*)(hT + (size_t)(w * 32 + d) * NN + ibase + half * 8) = v;
}

// volatile 16B load with compile-time immediate offset
template<int OFF>
__device__ __forceinline__ u32x4 gld(const void* p) {
    u32x4 d;
    asm volatile("global_load_dwordx4 %0, %1, off offset:%c2"
                 : "=&v"(d) : "v"(p), "n"(OFF));
    return d;
}

// per-step payload: 8 table regs + 2 mask regs = 10 x u32x4 = 40 VGPR/slot
struct SR { u32x4 h0k0, h0k1, h1k0, h1k1, bd00, bd01, bd10, bd11, ma, mb; };

#define LOADSET(S, T) do {                                                       \
    (S).h0k0 = gld<(T)*128      >(h0b); (S).h0k1 = gld<(T)*128 +  64>(h0b);      \
    (S).h1k0 = gld<(T)*128      >(h1b); (S).h1k1 = gld<(T)*128 +  64>(h1b);      \
    (S).bd00 = gld<(T)*256      >(bd);  (S).bd01 = gld<(T)*256 +  16>(bd);       \
    (S).bd10 = gld<(T)*256 + 128>(bd);  (S).bd11 = gld<(T)*256 + 144>(bd);       \
    (S).ma   = gld<((T)>>2)*32    >(pm0); (S).mb  = gld<((T)>>2)*32 + 16>(pm0);  \
} while (0)

#define LAUNDER(s) asm volatile("" : "+v"((s).h0k0), "+v"((s).h0k1),             \
    "+v"((s).h1k0), "+v"((s).h1k1), "+v"((s).bd00), "+v"((s).bd01),              \
    "+v"((s).bd10), "+v"((s).bd11), "+v"((s).ma), "+v"((s).mb))

// q = maskbit * max(B, R*D). Mask word/dword selection is compile-time (L0);
// per-elem: shift+and (bit) + neg-mask + and, plus mul/max — ~6 VALU/elem.
__device__ __forceinline__ short8 buildQb(float R, const u32x4 ba, const u32x4 bb,
                                          const u32x4 ma, const u32x4 mb,
                                          const int L0, const int shb) {
    const bool hi = (L0 >= 32);
    const int l0 = L0 & 31;
    unsigned wsel[4];
    wsel[0] = hi ? ma[1] : ma[0];
    wsel[1] = hi ? ma[3] : ma[2];
    wsel[2] = hi ? mb[1] : mb[0];
    wsel[3] = hi ? mb[3] : mb[2];
    float p[8];
#pragma unroll
    for (int e = 0; e < 8; ++e) {
        const unsigned v = (e < 4) ? ba[e] : bb[e - 4];
        const float B = __builtin_bit_cast(float, v << 16);
        const float D = __builtin_bit_cast(float, v & 0xFFFF0000u);
        const float m = fmaxf(B, R * D);
        const unsigned bit = (wsel[e & 3] >> (l0 + shb + (e >> 2))) & 1u;
        p[e] = __builtin_bit_cast(float, __builtin_bit_cast(unsigned, m) & (0u - bit));
    }
    u32x4 u = {pk2(p[0], p[1]), pk2(p[2], p[3]), pk2(p[4], p[5]), pk2(p[6], p[7])};
    return __builtin_bit_cast(short8, u);
}

// Kernel 3: grid (4 heads, 256 i-tiles of 16 rows, SJ) x 64 thr.
// ONE WAVE PER BLOCK, NO LDS, NO BARRIERS. adj comes from the 2 MB bitmask
// (L2/L3-resident even with 4x head duplication). All loads are volatile-asm
// with immediate offsets; 3 rotating register slots, depth-2, vmcnt(10),
// launder after each wait. Waves fully self-paced; stalls decorrelate.
__global__ __launch_bounds__(64) void k3_main(
        const unsigned long long* __restrict__ maskv,
        const unsigned short* __restrict__ hT,
        const float* __restrict__ Rt, const unsigned* __restrict__ BDt,
        float* __restrict__ numer, float* __restrict__ denom) {
    const int head = blockIdx.x;
    const int ibase = blockIdx.y * 16;
    const int jstart = blockIdx.z * JCH;
    const int lane = threadIdx.x;
    const int grp = lane >> 4, li = lane & 15;
    const int shb = grp * 2;

    const float R0 = Rt[head * NN + ibase + li];
    const unsigned short* h0b = hT + (size_t)(head * 32 + li) * NN + jstart + grp * 8;
    const unsigned short* h1b = h0b + (size_t)16 * NN;
    const unsigned* bd = BDt + head * NN + jstart + grp * 8;
    // mask row li of this i-tile; 4 u64 per 256-j chunk, 2 chunks per 512-j JCH
    const unsigned long long* pm0 = maskv + (size_t)(ibase + li) * 64 + (jstart >> 8) * 4;

    f32x4 c0 = {0.f,0.f,0.f,0.f}, c1 = {0.f,0.f,0.f,0.f}, dn = {0.f,0.f,0.f,0.f};
    short8 bones;
#pragma unroll
    for (int e = 0; e < 8; ++e) bones[e] = (short)0x3F80;  // bf16 1.0

    SR s0, s1, s2;

#define COMPUTE(S, T) do {                                                       \
    _Pragma("unroll")                                                            \
    for (int ks = 0; ks < 2; ++ks) {                                             \
        const u32x4 ba = ks ? (S).bd10 : (S).bd00;                               \
        const u32x4 bb = ks ? (S).bd11 : (S).bd01;                               \
        const short8 tA = __builtin_bit_cast(short8, ks ? (S).h0k1 : (S).h0k0);  \
        const short8 tB = __builtin_bit_cast(short8, ks ? (S).h1k1 : (S).h1k0);  \
        const short8 A = buildQb(R0, ba, bb, (S).ma, (S).mb,                     \
                                 ((T) & 3) * 16 + ks * 8, shb);                  \
        c0 = __builtin_amdgcn_mfma_f32_16x16x32_bf16(A, tA, c0, 0, 0, 0);        \
        c1 = __builtin_amdgcn_mfma_f32_16x16x32_bf16(A, tB, c1, 0, 0, 0);        \
        dn = __builtin_amdgcn_mfma_f32_16x16x32_bf16(A, bones, dn, 0, 0, 0);     \
    }                                                                            \
} while (0)

#define STEP(T, CUR, NXT, FAR) do {                                              \
    if ((T) + 2 < NSTEPS) {                                                      \
        LOADSET(FAR, (T) + 2);                                                   \
        __builtin_amdgcn_sched_barrier(0);                                       \
    }                                                                            \
    COMPUTE(CUR, T);                                                             \
    if ((T) + 1 < NSTEPS) {                                                      \
        if ((T) + 2 < NSTEPS) {                                                  \
            asm volatile("s_waitcnt vmcnt(10)" ::: "memory");                    \
        } else {                                                                 \
            asm volatile("s_waitcnt vmcnt(0)" ::: "memory");                     \
        }                                                                        \
        LAUNDER(NXT);                                                            \
        __builtin_amdgcn_sched_barrier(0);                                       \
    }                                                                            \
} while (0)

    // prologue: sets 0 and 1 in flight; drain set0, keep set1 pending
    LOADSET(s0, 0);
    __builtin_amdgcn_sched_barrier(0);
    LOADSET(s1, 1);
    __builtin_amdgcn_sched_barrier(0);
    asm volatile("s_waitcnt vmcnt(10)" ::: "memory");
    LAUNDER(s0);
    __builtin_amdgcn_sched_barrier(0);

    STEP(0, s0, s1, s2);
    STEP(1, s1, s2, s0);
    STEP(2, s2, s0, s1);
    STEP(3, s0, s1, s2);
    STEP(4, s1, s2, s0);
    STEP(5, s2, s0, s1);
    STEP(6, s0, s1, s2);
    STEP(7, s1, s2, s0);
#undef STEP
#undef COMPUTE

    // Epilogue: C layout col=li, row=grp*4+r.
    const int r0 = ibase + grp * 4;
    float* nb = numer + head * 32 + li;
#pragma unroll
    for (int r = 0; r < 4; ++r) {
        atomicAdd(nb + (size_t)(r0 + r) * 128, c0[r]);
        atomicAdd(nb + (size_t)(r0 + r) * 128 + 16, c1[r]);
    }
    if (li == 0) {
#pragma unroll
        for (int r = 0; r < 4; ++r)
            atomicAdd(denom + (r0 + r) * 4 + head, dn[r]);
    }
}

// Kernel 4: out = numer / denom
__global__ __launch_bounds__(256) void k4_fin(const float* __restrict__ numer,
                                              const float* __restrict__ denom,
                                              float* __restrict__ out) {
    const int idx = blockIdx.x * 256 + threadIdx.x;
    const int node = idx >> 7;
    const int headc = (idx & 127) >> 5;
    out[idx] = numer[idx] / denom[node * 4 + headc];
}

extern "C" void kernel_launch(void* const* d_in, const int* in_sizes, int n_in,
                              void* d_out, int out_size, void* d_ws, size_t ws_size,
                              hipStream_t stream) {
    const float* x = (const float*)d_in[0];
    const int* adj = (const int*)d_in[1];
    const float* W = (const float*)d_in[2];
    const float* asrc = (const float*)d_in[3];
    const float* adst = (const float*)d_in[4];
    float* out = (float*)d_out;

    char* ws = (char*)d_ws;
    float* numer = (float*)ws;                                     // 2 MB
    float* denom = (float*)(ws + (size_t)2097152);                 // 64 KB
    float* Rt = (float*)(ws + (size_t)2097152 + 65536);            // 64 KB
    unsigned* BDt = (unsigned*)(ws + (size_t)2097152 + 131072);    // 64 KB
    unsigned short* hT = (unsigned short*)(ws + (size_t)2097152 + 196608);          // 1 MB
    unsigned long long* maskv = (unsigned long long*)(ws + (size_t)2097152 + 196608 + 1048576);  // 2 MB

    (void)hipMemsetAsync(numer, 0, 2097152 + 65536, stream);       // zero accumulators
    k0_mask<<<1024, 256, 0, stream>>>(adj, maskv);
    k1_proj<<<256, 256, 0, stream>>>(x, W, asrc, adst, hT, Rt, BDt);
    k3_main<<<dim3(4, 256, SJ), 64, 0, stream>>>(maskv, hT, Rt, BDt, numer, denom);
    k4_fin<<<2048, 256, 0, stream>>>(numer, denom, out);
}